// Round 3
// baseline (102.285 us; speedup 1.0000x reference)
//
#include <hip/hip_runtime.h>

#define GRIDN 31
#define ROW   961            // 31*31
#define BJ    65536          // 1024 * 64 rows
#define NPAIRS (BJ / 2)      // 32768 row-pairs, each 1922 floats = 961 float2
#define WPB 4                // waves per block
#define PPW 2                // pairs per wave, fully unrolled
#define NBLOCKS (NPAIRS / (WPB * PPW))   // 4096

__global__ __launch_bounds__(256, 1) void soft_argmax_loss_kernel(
    const float* __restrict__ pred,
    const float* __restrict__ gt,
    float* __restrict__ out)
{
    const int lane = threadIdx.x & 63;
    const int wave = threadIdx.x >> 6;
    const int gw   = blockIdx.x * WPB + wave;

    // ---- hoisted weights: fixed per (lane, k, c) across ALL pairs ----
    // slot j = lane + 64k covers elements e = 2j, 2j+1 of the 1922-elem pair.
    // e < 961 -> row A; e >= 961 -> row B with e' = e - 961 (e==961 -> w=(0,0)).
    float wx[16][2], wy[16][2];
    #pragma unroll
    for (int k = 0; k < 16; ++k) {
        const int j = lane + 64 * k;
        #pragma unroll
        for (int c = 0; c < 2; ++c) {
            int e  = 2 * j + c;
            int ep = (e >= ROW) ? (e - ROW) : e;
            int y  = ep / GRIDN;
            int x  = ep - GRIDN * y;
            bool valid = (j <= 960);                 // k=15: only lane 0 real
            wx[k][c] = valid ? (float)x : 0.0f;
            wy[k][c] = valid ? (float)y : 0.0f;
        }
    }

    const float2* __restrict__ p2 = (const float2*)pred;
    const float2* __restrict__ g2 = (const float2*)gt;

    float dxA[PPW], dyA[PPW], dxB[PPW], dyB[PPW], dxM[PPW], dyM[PPW];
    #pragma unroll
    for (int pr = 0; pr < PPW; ++pr) {
        dxA[pr] = dyA[pr] = dxB[pr] = dyB[pr] = dxM[pr] = dyM[pr] = 0.0f;
    }

    // ---- load + accumulate phase (fully unrolled: max loads in flight) ----
    #pragma unroll
    for (int pr = 0; pr < PPW; ++pr) {
        const int P = gw * PPW + pr;
        const size_t base = (size_t)P * ROW;         // float2 units

        #pragma unroll
        for (int k = 0; k < 16; ++k) {
            const int j  = lane + 64 * k;
            const int jc = (k == 15) ? 960 : j;      // clamp tail (weights 0 off-lane0)
            float2 pv = p2[base + jc];
            float2 gv = g2[base + jc];
            float d0 = pv.x - gv.x;
            float d1 = pv.y - gv.y;
            if (k <= 6) {
                dxA[pr] = fmaf(d0, wx[k][0], dxA[pr]); dyA[pr] = fmaf(d0, wy[k][0], dyA[pr]);
                dxA[pr] = fmaf(d1, wx[k][1], dxA[pr]); dyA[pr] = fmaf(d1, wy[k][1], dyA[pr]);
            } else if (k == 7) {
                dxM[pr] = fmaf(d0, wx[k][0], dxM[pr]); dyM[pr] = fmaf(d0, wy[k][0], dyM[pr]);
                dxM[pr] = fmaf(d1, wx[k][1], dxM[pr]); dyM[pr] = fmaf(d1, wy[k][1], dyM[pr]);
            } else {
                dxB[pr] = fmaf(d0, wx[k][0], dxB[pr]); dyB[pr] = fmaf(d0, wy[k][0], dyB[pr]);
                dxB[pr] = fmaf(d1, wx[k][1], dxB[pr]); dyB[pr] = fmaf(d1, wy[k][1], dyB[pr]);
            }
        }
    }

    // ---- deferred reduction epilogue ----
    const bool toA = (lane <= 32);   // route mixed k==7 slot
    float wsum = 0.0f;
    #pragma unroll
    for (int pr = 0; pr < PPW; ++pr) {
        float ax = dxA[pr] + (toA ? dxM[pr] : 0.f);
        float ay = dyA[pr] + (toA ? dyM[pr] : 0.f);
        float bx = dxB[pr] + (toA ? 0.f : dxM[pr]);
        float by = dyB[pr] + (toA ? 0.f : dyM[pr]);
        #pragma unroll
        for (int off = 32; off; off >>= 1) {
            ax += __shfl_xor(ax, off); ay += __shfl_xor(ay, off);
            bx += __shfl_xor(bx, off); by += __shfl_xor(by, off);
        }
        const float s31 = 1.0f / 31.0f;
        float axs = ax * s31, ays = ay * s31;
        float bxs = bx * s31, bys = by * s31;
        wsum += 0.5f * (sqrtf(axs * axs + ays * ays) + sqrtf(bxs * bxs + bys * bys));
    }

    __shared__ float s[WPB];
    if (lane == 0) s[wave] = wsum;
    __syncthreads();
    if (threadIdx.x == 0) {
        atomicAdd(out, (s[0] + s[1] + s[2] + s[3]) * (1.0f / (float)BJ));
    }
}

extern "C" void kernel_launch(void* const* d_in, const int* in_sizes, int n_in,
                              void* d_out, int out_size, void* d_ws, size_t ws_size,
                              hipStream_t stream) {
    const float* pred = (const float*)d_in[0];
    const float* gt   = (const float*)d_in[1];
    float* out = (float*)d_out;

    // d_out is poisoned once and never re-poisoned between replays: zero it
    // every launch (async memset is graph-capture safe).
    hipMemsetAsync(out, 0, sizeof(float), stream);

    soft_argmax_loss_kernel<<<NBLOCKS, 256, 0, stream>>>(pred, gt, out);
}

// Round 4
// 99.076 us; speedup vs baseline: 1.0324x; 1.0324x over previous
//
#include <hip/hip_runtime.h>

#define GRIDN 31
#define ROW   961              // 31*31 floats per heatmap
#define BJ    65536            // 1024*64 rows
#define TROWS 4                // rows staged per round (3844 floats = 961 float4)
#define ROUNDS 8
#define NBLOCKS (BJ / (TROWS * ROUNDS))   // 2048
#define LDSF 3880              // 3844 + pad (tail reads, zero-masked)

// counted waits: N literal in the asm string
#define WAIT_VM8() asm volatile("s_waitcnt vmcnt(8)" ::: "memory")
#define WAIT_VM0() asm volatile("s_waitcnt vmcnt(0)" ::: "memory")
#define CFENCE()   asm volatile("" ::: "memory")

__global__ __launch_bounds__(256, 2) void soft_argmax_loss_kernel(
    const float* __restrict__ pred,
    const float* __restrict__ gt,
    float* __restrict__ out)
{
    // [buf][input][float] — staged contiguously by global_load_lds (linear dest)
    __shared__ float lds[2][2][LDSF];
    __shared__ float sred[4];

    const int t    = threadIdx.x;
    const int lane = t & 63;
    const int wave = t >> 6;
    const int c    = lane & 31;     // column 0..31 (31 = masked spare)
    const int h    = lane >> 5;     // y-parity half

    const float4* p4 = (const float4*)pred;
    const float4* g4 = (const float4*)gt;
    const int baseRow = blockIdx.x * (ROUNDS * TROWS);

    // issue one round's staging: 961 float4 per input, 16 B/lane direct-to-LDS.
    // dest = uniform(wave,i) + lane*16 — exactly the HW pattern (linear, no pad).
    auto issue = [&](int r, int b) {
        const int base4 = (baseRow + r * TROWS) * (ROW / 4) + (baseRow + r * TROWS) * 0
                        + ((baseRow + r * TROWS) * ROW) % 4; // (ROW*TROWS)%4==0, kept simple below
        const int b4 = ((baseRow + r * TROWS) * ROW) >> 2;   // float4 index, exact
        #pragma unroll
        for (int i = 0; i < 4; ++i) {
            const int m = t + 256 * i;
            if (m < 961) {   // i<3 compile-time true; i==3 masks t>=193
                __builtin_amdgcn_global_load_lds(
                    (const __attribute__((address_space(1))) void*)(p4 + b4 + m),
                    (__attribute__((address_space(3))) void*)&lds[b][0][4 * m], 16, 0, 0);
                __builtin_amdgcn_global_load_lds(
                    (const __attribute__((address_space(1))) void*)(g4 + b4 + m),
                    (__attribute__((address_space(3))) void*)&lds[b][1][4 * m], 16, 0, 0);
            }
        }
        (void)base4;
    };

    // per-lane constants
    const float cF = (float)c;
    const float hF = (float)h;
    const float mA = (c < 31) ? 1.0f : 0.0f;               // spare-column mask
    const float mB = (c < 31 && h == 0) ? 1.0f : 0.0f;     // last iter: y=31 invalid for h=1

    float wsum = 0.0f;

    issue(0, 0);   // prologue

    #pragma unroll 1
    for (int r = 0; r < ROUNDS; ++r) {
        const int b = r & 1;
        if (r + 1 < ROUNDS) {
            issue(r + 1, b ^ 1);   // next round in flight across the barrier
            WAIT_VM8();            // round r's 8 issues complete; next 8 stay in flight
        } else {
            WAIT_VM0();
        }
        __builtin_amdgcn_s_barrier();

        // wave w owns row w of this round. lane (c,h): elements e = (2i+h)*31 + c
        const int rbase = wave * ROW + 31 * h + c;
        const float* lp = &lds[b][0][rbase];
        const float* lg = &lds[b][1][rbase];

        float dx = 0.f, dyA = 0.f, dS = 0.f;
        #pragma unroll
        for (int i = 0; i < 16; ++i) {
            const float pv = lp[62 * i];
            const float gv = lg[62 * i];
            float d = (pv - gv) * ((i == 15) ? mB : mA);
            dx  = fmaf(d, cF, dx);
            dyA = fmaf(d, (float)(2 * i), dyA);   // y = 2i + h; literal part
            dS += d;
        }
        float dy = fmaf(hF, dS, dyA);             // + h * sum(d)

        // full-wave butterfly: every lane ends with the row totals
        #pragma unroll
        for (int off = 32; off; off >>= 1) {
            dx += __shfl_xor(dx, off);
            dy += __shfl_xor(dy, off);
        }
        const float s31 = 1.0f / 31.0f;
        const float ax = dx * s31, ay = dy * s31;
        wsum += 0.5f * sqrtf(ax * ax + ay * ay);  // uniform across the wave

        CFENCE();                                  // keep LDS reads above the barrier
        __builtin_amdgcn_s_barrier();              // buffer b free for round r+2's issue
    }

    if (lane == 0) sred[wave] = wsum;
    __syncthreads();
    if (t == 0) {
        atomicAdd(out, (sred[0] + sred[1] + sred[2] + sred[3]) * (1.0f / (float)BJ));
    }
}

extern "C" void kernel_launch(void* const* d_in, const int* in_sizes, int n_in,
                              void* d_out, int out_size, void* d_ws, size_t ws_size,
                              hipStream_t stream) {
    const float* pred = (const float*)d_in[0];
    const float* gt   = (const float*)d_in[1];
    float* out = (float*)d_out;

    // d_out poisoned once, never re-poisoned between replays: zero every launch.
    hipMemsetAsync(out, 0, sizeof(float), stream);

    soft_argmax_loss_kernel<<<NBLOCKS, 256, 0, stream>>>(pred, gt, out);
}

// Round 6
// 81.595 us; speedup vs baseline: 1.2536x; 1.2142x over previous
//
#include <hip/hip_runtime.h>

#define GRIDN 31
#define ROW   961            // 31*31
#define BJ    65536          // 1024 * 64 rows
#define NPAIRS (BJ / 2)      // 32768 row-pairs, each 1922 floats = 961 float2
#define NBLOCKS 2048
#define WPB 4                // waves per block
#define PAIRS_PER_WAVE (NPAIRS / (NBLOCKS * WPB))   // 4

typedef float v2f __attribute__((ext_vector_type(2)));   // builtin-compatible

__global__ __launch_bounds__(256) void soft_argmax_loss_kernel(
    const float* __restrict__ pred,
    const float* __restrict__ gt,
    float* __restrict__ out)
{
    const int lane = threadIdx.x & 63;
    const int wave = threadIdx.x >> 6;
    const int gw   = blockIdx.x * WPB + wave;       // 0..8191

    // ---- hoisted weights: fixed per (lane, k, c) across ALL pairs ----
    // slot j = lane + 64k covers elements e = 2j, 2j+1 of the 1922-elem pair.
    // e < 961 -> row A, e >= 961 -> row B with e' = e - 961.
    // (e == 961 has (x,y) = (0,0): zero contribution, routing irrelevant.)
    float wx[16][2], wy[16][2];
    #pragma unroll
    for (int k = 0; k < 16; ++k) {
        const int j = lane + 64 * k;
        #pragma unroll
        for (int c = 0; c < 2; ++c) {
            int e  = 2 * j + c;
            int ep = (e >= ROW) ? (e - ROW) : e;
            int y  = ep / GRIDN;
            int x  = ep - GRIDN * y;
            bool valid = (j <= 960);                 // k=15: only lane 0 real
            wx[k][c] = valid ? (float)x : 0.0f;
            wy[k][c] = valid ? (float)y : 0.0f;
        }
    }

    const v2f* __restrict__ p2 = (const v2f*)pred;
    const v2f* __restrict__ g2 = (const v2f*)gt;

    float wsum = 0.0f;

    #pragma unroll 1
    for (int pr = 0; pr < PAIRS_PER_WAVE; ++pr) {
        const int P = gw * PAIRS_PER_WAVE + pr;
        const size_t base = (size_t)P * ROW;         // in float2 units

        float dxA = 0.f, dyA = 0.f;                  // row 2P
        float dxM = 0.f, dyM = 0.f;                  // k==7 mixed slot
        float dxB = 0.f, dyB = 0.f;                  // row 2P+1

        #pragma unroll
        for (int k = 0; k < 16; ++k) {
            const int j  = lane + 64 * k;
            const int jc = (k == 15) ? 960 : j;      // clamp tail (weights 0 off-lane0)
            // pred: NON-TEMPORAL (nt) — stream, don't allocate in cache, so it
            // cannot victimize the (hopefully L3-resident) target input.
            v2f pv = __builtin_nontemporal_load(&p2[base + jc]);
            // target: normal cached load — 252 MB fits the 256 MB L3.
            v2f gv = g2[base + jc];
            float d0 = pv.x - gv.x;
            float d1 = pv.y - gv.y;
            if (k <= 6) {
                dxA = fmaf(d0, wx[k][0], dxA); dyA = fmaf(d0, wy[k][0], dyA);
                dxA = fmaf(d1, wx[k][1], dxA); dyA = fmaf(d1, wy[k][1], dyA);
            } else if (k == 7) {
                dxM = fmaf(d0, wx[k][0], dxM); dyM = fmaf(d0, wy[k][0], dyM);
                dxM = fmaf(d1, wx[k][1], dxM); dyM = fmaf(d1, wy[k][1], dyM);
            } else {
                dxB = fmaf(d0, wx[k][0], dxB); dyB = fmaf(d0, wy[k][0], dyB);
                dxB = fmaf(d1, wx[k][1], dxB); dyB = fmaf(d1, wy[k][1], dyB);
            }
        }

        // route the mixed k==7 slot: lanes 0..32 -> row A, 33..63 -> row B
        const bool toA = (lane <= 32);
        dxA += toA ? dxM : 0.f;  dyA += toA ? dyM : 0.f;
        dxB += toA ? 0.f : dxM;  dyB += toA ? 0.f : dyM;

        // wave butterfly reduce (4 values)
        #pragma unroll
        for (int off = 32; off; off >>= 1) {
            dxA += __shfl_xor(dxA, off); dyA += __shfl_xor(dyA, off);
            dxB += __shfl_xor(dxB, off); dyB += __shfl_xor(dyB, off);
        }

        const float s31 = 1.0f / 31.0f;
        float ax = dxA * s31, ay = dyA * s31;
        float bx = dxB * s31, by = dyB * s31;
        wsum += 0.5f * (sqrtf(ax * ax + ay * ay) + sqrtf(bx * bx + by * by));
    }

    __shared__ float s[WPB];
    if (lane == 0) s[wave] = wsum;
    __syncthreads();
    if (threadIdx.x == 0) {
        atomicAdd(out, (s[0] + s[1] + s[2] + s[3]) * (1.0f / (float)BJ));
    }
}

extern "C" void kernel_launch(void* const* d_in, const int* in_sizes, int n_in,
                              void* d_out, int out_size, void* d_ws, size_t ws_size,
                              hipStream_t stream) {
    const float* pred = (const float*)d_in[0];
    const float* gt   = (const float*)d_in[1];
    float* out = (float*)d_out;

    // d_out is poisoned once and never re-poisoned between replays: zero it
    // every launch (async memset is graph-capture safe).
    (void)hipMemsetAsync(out, 0, sizeof(float), stream);

    soft_argmax_loss_kernel<<<NBLOCKS, 256, 0, stream>>>(pred, gt, out);
}